// Round 1
// baseline (584.313 us; speedup 1.0000x reference)
//
#include <hip/hip_runtime.h>

// Problem constants
#define NB   8        // batch
#define NPT  8192     // N query points
#define NS   2048     // S source points
#define ND1  128      // points1 channels
#define ND2  256      // points2 channels
#define NIN  384      // concat channels
#define NC0  256      // MLP[0]
#define NC1  128      // MLP[1]
#define NBN  (NB*NPT) // 65536 total columns

// ---------------------------------------------------------------------------
// Kernel 1: 3-NN search + inverse-distance weights.
// grid (NB, 64), 256 threads. Block handles 128 query points; 2 threads per
// query, each scanning half of the S=2048 candidates; top-3 merged in LDS.
// ---------------------------------------------------------------------------
__global__ __launch_bounds__(256) void knn_kernel(
    const float* __restrict__ xyz1, const float* __restrict__ xyz2,
    int* __restrict__ idx3, float* __restrict__ wgt3)
{
    __shared__ float sx[NS], sy[NS], sz[NS], sq[NS];
    __shared__ float md[128][2][3];
    __shared__ int   mi[128][2][3];

    const int b     = blockIdx.x;
    const int ntile = blockIdx.y;
    const float* x2 = xyz2 + (size_t)b * 3 * NS;
    for (int s = threadIdx.x; s < NS; s += 256) {
        float x = x2[s], y = x2[NS + s], z = x2[2 * NS + s];
        sx[s] = x; sy[s] = y; sz[s] = z; sq[s] = x * x + y * y + z * z;
    }
    __syncthreads();

    const int nl   = threadIdx.x & 127;
    const int half = threadIdx.x >> 7;
    const int n    = ntile * 128 + nl;
    const float* x1 = xyz1 + (size_t)b * 3 * NPT;
    const float px = x1[n], py = x1[NPT + n], pz = x1[2 * NPT + n];
    const float p1sq = px * px + py * py + pz * pz;

    float d0 = 3e38f, d1 = 3e38f, d2 = 3e38f;
    int   i0 = 0, i1 = 0, i2 = 0;
    const int sbeg = half * (NS / 2);
    for (int s = sbeg; s < sbeg + NS / 2; ++s) {
        float d = p1sq + sq[s] - 2.0f * (px * sx[s] + py * sy[s] + pz * sz[s]);
        if (d < d2) {
            if (d < d1) {
                d2 = d1; i2 = i1;
                if (d < d0) { d1 = d0; i1 = i0; d0 = d; i0 = s; }
                else        { d1 = d;  i1 = s; }
            } else { d2 = d; i2 = s; }
        }
    }
    md[nl][half][0] = d0; md[nl][half][1] = d1; md[nl][half][2] = d2;
    mi[nl][half][0] = i0; mi[nl][half][1] = i1; mi[nl][half][2] = i2;
    __syncthreads();

    if (threadIdx.x < 128) {
        // merge two sorted triples; ties prefer list 0 (lower indices) to
        // match lax.top_k's lowest-index tie-break.
        int ia = 0, ib = 0;
        float rd[3]; int ri[3];
        #pragma unroll
        for (int k = 0; k < 3; ++k) {
            float da = md[nl][0][ia], db = md[nl][1][ib];
            if (da <= db) { rd[k] = da; ri[k] = mi[nl][0][ia]; ++ia; }
            else          { rd[k] = db; ri[k] = mi[nl][1][ib]; ++ib; }
        }
        float r0 = 1.0f / (rd[0] + 1e-8f);
        float r1 = 1.0f / (rd[1] + 1e-8f);
        float r2 = 1.0f / (rd[2] + 1e-8f);
        float inv = 1.0f / (r0 + r1 + r2);
        size_t base = ((size_t)b * NPT + n) * 3;
        idx3[base] = ri[0]; idx3[base + 1] = ri[1]; idx3[base + 2] = ri[2];
        wgt3[base] = r0 * inv; wgt3[base + 1] = r1 * inv; wgt3[base + 2] = r2 * inv;
    }
}

// ---------------------------------------------------------------------------
// Kernel 2: feature interpolation. grid (NB, 32), 256 threads.
// Thread owns query n, loops over all 256 channels; writes coalesced along n.
// ---------------------------------------------------------------------------
__global__ __launch_bounds__(256) void interp_kernel(
    const float* __restrict__ points2, const int* __restrict__ idx3,
    const float* __restrict__ wgt3, float* __restrict__ interp)
{
    const int b = blockIdx.x;
    const int n = blockIdx.y * 256 + threadIdx.x;
    const size_t base = ((size_t)b * NPT + n) * 3;
    const int i0 = idx3[base], i1 = idx3[base + 1], i2 = idx3[base + 2];
    const float w0 = wgt3[base], w1 = wgt3[base + 1], w2 = wgt3[base + 2];
    const float* p2 = points2 + (size_t)b * ND2 * NS;
    float* dst = interp + (size_t)b * ND2 * NPT + n;
    for (int d = 0; d < ND2; ++d) {
        const float* row = p2 + (size_t)d * NS;
        dst[(size_t)d * NPT] = w0 * row[i0] + w1 * row[i1] + w2 * row[i2];
    }
}

// ---------------------------------------------------------------------------
// Kernel 3: GEMM layer 0 (Y[o,bn] = sum_c W[o,c] X[c,bn] + bias), X = concat
// of points1 / interp. Fused per-channel sum/sumsq accumulation (atomics).
// 64x64 tile, BK=16, 256 threads, 4x4 per thread.
// grid (NBN/64, NC0/64).
// ---------------------------------------------------------------------------
__global__ __launch_bounds__(256) void gemm0_kernel(
    const float* __restrict__ W, const float* __restrict__ bias,
    const float* __restrict__ points1, const float* __restrict__ interp,
    float* __restrict__ Y, float* __restrict__ sums, float* __restrict__ sumsq)
{
    __shared__ float As[16][64];   // [k][m]
    __shared__ float Bs[16][64];   // [k][n]
    const int tid = threadIdx.x;
    const int tx = tid & 15, ty = tid >> 4;
    const int bn0 = blockIdx.x * 64;
    const int o0  = blockIdx.y * 64;
    const int b    = bn0 / NPT;
    const int nloc = bn0 % NPT;
    const int am = tid >> 2;           // 0..63
    const int ak = (tid & 3) * 4;      // 0,4,8,12
    const int br = tid >> 4;           // 0..15
    const int bc = (tid & 15) * 4;     // 0..60
    float acc[4][4] = {};

    for (int k0 = 0; k0 < NIN; k0 += 16) {
        float4 av = *reinterpret_cast<const float4*>(&W[(size_t)(o0 + am) * NIN + k0 + ak]);
        const int c = k0 + br;
        const float* src = (c < ND1)
            ? (points1 + ((size_t)b * ND1 + c) * NPT + nloc + bc)
            : (interp  + ((size_t)b * ND2 + (c - ND1)) * NPT + nloc + bc);
        float4 bv = *reinterpret_cast<const float4*>(src);
        As[ak + 0][am] = av.x; As[ak + 1][am] = av.y;
        As[ak + 2][am] = av.z; As[ak + 3][am] = av.w;
        *reinterpret_cast<float4*>(&Bs[br][bc]) = bv;
        __syncthreads();
        #pragma unroll
        for (int k = 0; k < 16; ++k) {
            float a0 = As[k][ty * 4 + 0], a1 = As[k][ty * 4 + 1];
            float a2 = As[k][ty * 4 + 2], a3 = As[k][ty * 4 + 3];
            float x0 = Bs[k][tx * 4 + 0], x1 = Bs[k][tx * 4 + 1];
            float x2 = Bs[k][tx * 4 + 2], x3 = Bs[k][tx * 4 + 3];
            acc[0][0] += a0 * x0; acc[0][1] += a0 * x1; acc[0][2] += a0 * x2; acc[0][3] += a0 * x3;
            acc[1][0] += a1 * x0; acc[1][1] += a1 * x1; acc[1][2] += a1 * x2; acc[1][3] += a1 * x3;
            acc[2][0] += a2 * x0; acc[2][1] += a2 * x1; acc[2][2] += a2 * x2; acc[2][3] += a2 * x3;
            acc[3][0] += a3 * x0; acc[3][1] += a3 * x1; acc[3][2] += a3 * x2; acc[3][3] += a3 * x3;
        }
        __syncthreads();
    }

    float vals[4][4];
    #pragma unroll
    for (int i = 0; i < 4; ++i) {
        float bi = bias[o0 + ty * 4 + i];
        #pragma unroll
        for (int j = 0; j < 4; ++j) vals[i][j] = acc[i][j] + bi;
        *reinterpret_cast<float4*>(&Y[(size_t)(o0 + ty * 4 + i) * NBN + bn0 + tx * 4]) =
            *reinterpret_cast<float4*>(&vals[i][0]);
    }
    // per-channel stats: block reduce then atomics (64 channels/block)
    float* red1 = &As[0][0];
    float* red2 = &Bs[0][0];
    #pragma unroll
    for (int i = 0; i < 4; ++i) {
        float s = 0.f, q = 0.f;
        #pragma unroll
        for (int j = 0; j < 4; ++j) { float v = vals[i][j]; s += v; q += v * v; }
        red1[(ty * 4 + i) * 16 + tx] = s;
        red2[(ty * 4 + i) * 16 + tx] = q;
    }
    __syncthreads();
    if (tid < 64) {
        float s = 0.f, q = 0.f;
        #pragma unroll
        for (int t = 0; t < 16; ++t) { s += red1[tid * 16 + t]; q += red2[tid * 16 + t]; }
        atomicAdd(&sums[o0 + tid], s);
        atomicAdd(&sumsq[o0 + tid], q);
    }
}

// ---------------------------------------------------------------------------
// Kernel 4: finalize BN stats -> scale/shift
// ---------------------------------------------------------------------------
__global__ void stats_kernel(
    const float* __restrict__ sums, const float* __restrict__ sumsq,
    const float* __restrict__ g, const float* __restrict__ be,
    float* __restrict__ scale, float* __restrict__ shift, int C)
{
    int c = blockIdx.x * blockDim.x + threadIdx.x;
    if (c < C) {
        const float invN = 1.0f / (float)NBN;
        float mean = sums[c] * invN;
        float var  = sumsq[c] * invN - mean * mean;
        float sc   = g[c] * rsqrtf(var + 1e-5f);
        scale[c] = sc;
        shift[c] = be[c] - mean * sc;
    }
}

// ---------------------------------------------------------------------------
// Kernel 5: GEMM layer 1, X = relu(BN0(y0)) applied on load. Same structure.
// grid (NBN/64, NC1/64).
// ---------------------------------------------------------------------------
__global__ __launch_bounds__(256) void gemm1_kernel(
    const float* __restrict__ W, const float* __restrict__ bias,
    const float* __restrict__ y0,
    const float* __restrict__ scale0, const float* __restrict__ shift0,
    float* __restrict__ Y, float* __restrict__ sums, float* __restrict__ sumsq)
{
    __shared__ float As[16][64];
    __shared__ float Bs[16][64];
    const int tid = threadIdx.x;
    const int tx = tid & 15, ty = tid >> 4;
    const int bn0 = blockIdx.x * 64;
    const int o0  = blockIdx.y * 64;
    const int am = tid >> 2;
    const int ak = (tid & 3) * 4;
    const int br = tid >> 4;
    const int bc = (tid & 15) * 4;
    float acc[4][4] = {};

    for (int k0 = 0; k0 < NC0; k0 += 16) {
        float4 av = *reinterpret_cast<const float4*>(&W[(size_t)(o0 + am) * NC0 + k0 + ak]);
        const int c = k0 + br;
        float4 xv = *reinterpret_cast<const float4*>(&y0[(size_t)c * NBN + bn0 + bc]);
        float s = scale0[c], sh = shift0[c];
        float4 bv;
        bv.x = fmaxf(xv.x * s + sh, 0.f);
        bv.y = fmaxf(xv.y * s + sh, 0.f);
        bv.z = fmaxf(xv.z * s + sh, 0.f);
        bv.w = fmaxf(xv.w * s + sh, 0.f);
        As[ak + 0][am] = av.x; As[ak + 1][am] = av.y;
        As[ak + 2][am] = av.z; As[ak + 3][am] = av.w;
        *reinterpret_cast<float4*>(&Bs[br][bc]) = bv;
        __syncthreads();
        #pragma unroll
        for (int k = 0; k < 16; ++k) {
            float a0 = As[k][ty * 4 + 0], a1 = As[k][ty * 4 + 1];
            float a2 = As[k][ty * 4 + 2], a3 = As[k][ty * 4 + 3];
            float x0 = Bs[k][tx * 4 + 0], x1 = Bs[k][tx * 4 + 1];
            float x2 = Bs[k][tx * 4 + 2], x3 = Bs[k][tx * 4 + 3];
            acc[0][0] += a0 * x0; acc[0][1] += a0 * x1; acc[0][2] += a0 * x2; acc[0][3] += a0 * x3;
            acc[1][0] += a1 * x0; acc[1][1] += a1 * x1; acc[1][2] += a1 * x2; acc[1][3] += a1 * x3;
            acc[2][0] += a2 * x0; acc[2][1] += a2 * x1; acc[2][2] += a2 * x2; acc[2][3] += a2 * x3;
            acc[3][0] += a3 * x0; acc[3][1] += a3 * x1; acc[3][2] += a3 * x2; acc[3][3] += a3 * x3;
        }
        __syncthreads();
    }

    float vals[4][4];
    #pragma unroll
    for (int i = 0; i < 4; ++i) {
        float bi = bias[o0 + ty * 4 + i];
        #pragma unroll
        for (int j = 0; j < 4; ++j) vals[i][j] = acc[i][j] + bi;
        *reinterpret_cast<float4*>(&Y[(size_t)(o0 + ty * 4 + i) * NBN + bn0 + tx * 4]) =
            *reinterpret_cast<float4*>(&vals[i][0]);
    }
    float* red1 = &As[0][0];
    float* red2 = &Bs[0][0];
    #pragma unroll
    for (int i = 0; i < 4; ++i) {
        float s = 0.f, q = 0.f;
        #pragma unroll
        for (int j = 0; j < 4; ++j) { float v = vals[i][j]; s += v; q += v * v; }
        red1[(ty * 4 + i) * 16 + tx] = s;
        red2[(ty * 4 + i) * 16 + tx] = q;
    }
    __syncthreads();
    if (tid < 64) {
        float s = 0.f, q = 0.f;
        #pragma unroll
        for (int t = 0; t < 16; ++t) { s += red1[tid * 16 + t]; q += red2[tid * 16 + t]; }
        atomicAdd(&sums[o0 + tid], s);
        atomicAdd(&sumsq[o0 + tid], q);
    }
}

// ---------------------------------------------------------------------------
// Kernel 6: apply BN1 + ReLU, transpose [o][b*N+n] -> [b][o][n]
// ---------------------------------------------------------------------------
__global__ __launch_bounds__(256) void bnout_kernel(
    const float* __restrict__ y1, const float* __restrict__ scale1,
    const float* __restrict__ shift1, float* __restrict__ out)
{
    const size_t t = (size_t)blockIdx.x * 256 + threadIdx.x;
    const size_t e = t * 4;
    const int n = (int)(e & (NPT - 1));
    const int o = (int)((e >> 13) & (NC1 - 1));
    const int b = (int)(e >> 20);
    float4 v = *reinterpret_cast<const float4*>(&y1[(size_t)o * NBN + (size_t)b * NPT + n]);
    const float s = scale1[o], sh = shift1[o];
    float4 r;
    r.x = fmaxf(v.x * s + sh, 0.f);
    r.y = fmaxf(v.y * s + sh, 0.f);
    r.z = fmaxf(v.z * s + sh, 0.f);
    r.w = fmaxf(v.w * s + sh, 0.f);
    *reinterpret_cast<float4*>(&out[e]) = r;
}

// ---------------------------------------------------------------------------
extern "C" void kernel_launch(void* const* d_in, const int* in_sizes, int n_in,
                              void* d_out, int out_size, void* d_ws, size_t ws_size,
                              hipStream_t stream)
{
    const float* xyz1    = (const float*)d_in[0];
    const float* xyz2    = (const float*)d_in[1];
    const float* points1 = (const float*)d_in[2];
    const float* points2 = (const float*)d_in[3];
    const float* w0  = (const float*)d_in[4];
    const float* b0  = (const float*)d_in[5];
    const float* g0  = (const float*)d_in[6];
    const float* be0 = (const float*)d_in[7];
    const float* w1  = (const float*)d_in[8];
    const float* b1  = (const float*)d_in[9];
    const float* g1  = (const float*)d_in[10];
    const float* be1 = (const float*)d_in[11];

    char* ws = (char*)d_ws;
    size_t off = 0;
    int*   idx3   = (int*)(ws + off);   off += (size_t)NBN * 3 * 4;       // 786432
    float* wgt3   = (float*)(ws + off); off += (size_t)NBN * 3 * 4;       // 786432
    const size_t interp_off = off;
    float* interp = (float*)(ws + off); off += (size_t)NB * ND2 * NPT * 4; // 64 MB
    float* y0     = (float*)(ws + off); off += (size_t)NC0 * NBN * 4;      // 64 MB
    float* stats  = (float*)(ws + off);                                    // 1536 floats
    float* sums0  = stats;        float* sumsq0 = stats + 256;
    float* sums1  = stats + 512;  float* sumsq1 = stats + 640;
    float* scale0 = stats + 768;  float* shift0 = stats + 1024;
    float* scale1 = stats + 1280; float* shift1 = stats + 1408;
    float* y1     = (float*)(ws + interp_off); // reuse interp buffer

    hipMemsetAsync(stats, 0, 768 * 4, stream); // zero accumulators (ws is poisoned)

    knn_kernel   <<<dim3(NB, 64), 256, 0, stream>>>(xyz1, xyz2, idx3, wgt3);
    interp_kernel<<<dim3(NB, 32), 256, 0, stream>>>(points2, idx3, wgt3, interp);
    gemm0_kernel <<<dim3(NBN / 64, NC0 / 64), 256, 0, stream>>>(
        w0, b0, points1, interp, y0, sums0, sumsq0);
    stats_kernel <<<1, 256, 0, stream>>>(sums0, sumsq0, g0, be0, scale0, shift0, NC0);
    gemm1_kernel <<<dim3(NBN / 64, NC1 / 64), 256, 0, stream>>>(
        w1, b1, y0, scale0, shift0, y1, sums1, sumsq1);
    stats_kernel <<<1, 128, 0, stream>>>(sums1, sumsq1, g1, be1, scale1, shift1, NC1);
    bnout_kernel <<<dim3((size_t)NBN * NC1 / 4 / 256), 256, 0, stream>>>(
        y1, scale1, shift1, (float*)d_out);
}

// Round 2
// 455.645 us; speedup vs baseline: 1.2824x; 1.2824x over previous
//
#include <hip/hip_runtime.h>

// Problem constants
#define NB   8        // batch
#define NPT  8192     // N query points
#define NS   2048     // S source points
#define ND1  128      // points1 channels
#define ND2  256      // points2 channels
#define NIN  384      // concat channels
#define NC0  256      // MLP[0]
#define NC1  128      // MLP[1]
#define NBN  (NB*NPT) // 65536 total columns

typedef __bf16 bf16x8 __attribute__((ext_vector_type(8)));
typedef __bf16 bf16x4 __attribute__((ext_vector_type(4)));
typedef float  f32x4  __attribute__((ext_vector_type(4)));

// ---------------------------------------------------------------------------
// Kernel 1: 3-NN search + inverse-distance weights (unchanged, fp32-exact
// so neighbor indices match the reference).
// ---------------------------------------------------------------------------
__global__ __launch_bounds__(256) void knn_kernel(
    const float* __restrict__ xyz1, const float* __restrict__ xyz2,
    int* __restrict__ idx3, float* __restrict__ wgt3)
{
    __shared__ float sx[NS], sy[NS], sz[NS], sq[NS];
    __shared__ float md[128][2][3];
    __shared__ int   mi[128][2][3];

    const int b     = blockIdx.x;
    const int ntile = blockIdx.y;
    const float* x2 = xyz2 + (size_t)b * 3 * NS;
    for (int s = threadIdx.x; s < NS; s += 256) {
        float x = x2[s], y = x2[NS + s], z = x2[2 * NS + s];
        sx[s] = x; sy[s] = y; sz[s] = z; sq[s] = x * x + y * y + z * z;
    }
    __syncthreads();

    const int nl   = threadIdx.x & 127;
    const int half = threadIdx.x >> 7;
    const int n    = ntile * 128 + nl;
    const float* x1 = xyz1 + (size_t)b * 3 * NPT;
    const float px = x1[n], py = x1[NPT + n], pz = x1[2 * NPT + n];
    const float p1sq = px * px + py * py + pz * pz;

    float d0 = 3e38f, d1 = 3e38f, d2 = 3e38f;
    int   i0 = 0, i1 = 0, i2 = 0;
    const int sbeg = half * (NS / 2);
    for (int s = sbeg; s < sbeg + NS / 2; ++s) {
        float d = p1sq + sq[s] - 2.0f * (px * sx[s] + py * sy[s] + pz * sz[s]);
        if (d < d2) {
            if (d < d1) {
                d2 = d1; i2 = i1;
                if (d < d0) { d1 = d0; i1 = i0; d0 = d; i0 = s; }
                else        { d1 = d;  i1 = s; }
            } else { d2 = d; i2 = s; }
        }
    }
    md[nl][half][0] = d0; md[nl][half][1] = d1; md[nl][half][2] = d2;
    mi[nl][half][0] = i0; mi[nl][half][1] = i1; mi[nl][half][2] = i2;
    __syncthreads();

    if (threadIdx.x < 128) {
        int ia = 0, ib = 0;
        float rd[3]; int ri[3];
        #pragma unroll
        for (int k = 0; k < 3; ++k) {
            float da = md[nl][0][ia], db = md[nl][1][ib];
            if (da <= db) { rd[k] = da; ri[k] = mi[nl][0][ia]; ++ia; }
            else          { rd[k] = db; ri[k] = mi[nl][1][ib]; ++ib; }
        }
        float r0 = 1.0f / (rd[0] + 1e-8f);
        float r1 = 1.0f / (rd[1] + 1e-8f);
        float r2 = 1.0f / (rd[2] + 1e-8f);
        float inv = 1.0f / (r0 + r1 + r2);
        size_t base = ((size_t)b * NPT + n) * 3;
        idx3[base] = ri[0]; idx3[base + 1] = ri[1]; idx3[base + 2] = ri[2];
        wgt3[base] = r0 * inv; wgt3[base + 1] = r1 * inv; wgt3[base + 2] = r2 * inv;
    }
}

// ---------------------------------------------------------------------------
// Kernel 2: build Xc[n][c] bf16 = concat(points1, interp) TRANSPOSED so the
// MFMA B-operand (lane = fixed n, 8 contiguous k) is a direct 16B load.
// Thread owns column n; p1 reads coalesced along n; p2 gathers hit L2/L3.
// ---------------------------------------------------------------------------
__global__ __launch_bounds__(256) void build_xc_kernel(
    const float* __restrict__ points1, const float* __restrict__ points2,
    const int* __restrict__ idx3, const float* __restrict__ wgt3,
    __bf16* __restrict__ Xc)
{
    const int b = blockIdx.x;
    const int n = blockIdx.y * 256 + threadIdx.x;
    const size_t base3 = ((size_t)b * NPT + n) * 3;
    const int i0 = idx3[base3], i1 = idx3[base3 + 1], i2 = idx3[base3 + 2];
    const float w0 = wgt3[base3], w1 = wgt3[base3 + 1], w2 = wgt3[base3 + 2];

    __bf16* dst = Xc + ((size_t)b * NPT + n) * NIN;
    const float* p1 = points1 + (size_t)b * ND1 * NPT + n;
    for (int c0 = 0; c0 < ND1; c0 += 8) {
        bf16x8 v;
        #pragma unroll
        for (int j = 0; j < 8; ++j) v[j] = (__bf16)p1[(size_t)(c0 + j) * NPT];
        *(bf16x8*)(dst + c0) = v;
    }
    const float* p2 = points2 + (size_t)b * ND2 * NS;
    for (int d0 = 0; d0 < ND2; d0 += 8) {
        bf16x8 v;
        #pragma unroll
        for (int j = 0; j < 8; ++j) {
            const float* row = p2 + (size_t)(d0 + j) * NS;
            v[j] = (__bf16)(w0 * row[i0] + w1 * row[i1] + w2 * row[i2]);
        }
        *(bf16x8*)(dst + 128 + d0) = v;
    }
}

// ---------------------------------------------------------------------------
// Kernel 3: convert weights to bf16 [o][k] (k-contiguous = A-operand layout)
// ---------------------------------------------------------------------------
__global__ __launch_bounds__(256) void convert_w_kernel(
    const float* __restrict__ w0, const float* __restrict__ w1,
    __bf16* __restrict__ Wb0, __bf16* __restrict__ Wb1)
{
    const int t = blockIdx.x * 256 + threadIdx.x;
    if (t < NC0 * NIN) Wb0[t] = (__bf16)w0[t];
    if (t < NC1 * NC0) Wb1[t] = (__bf16)w1[t];
}

// ---------------------------------------------------------------------------
// Kernel 4: GEMM0 via 16x16x32 bf16 MFMA, LDS-free (operands k-contiguous in
// global). Block = 512 thr (8 waves, 4o x 2n), tile 256o x 128n, K=384.
// Writes y0[n][o] bf16 (gemm1's B layout). Bias skipped (BN cancels it).
// Per-channel sum/sumsq: shfl-reduce + LDS combine + 2 atomics/channel/block.
// ---------------------------------------------------------------------------
__global__ __launch_bounds__(512, 4) void gemm0_mfma(
    const __bf16* __restrict__ Wb, const __bf16* __restrict__ Xc,
    __bf16* __restrict__ y0, float* __restrict__ sums, float* __restrict__ sumsq)
{
    __shared__ float red[2][NC0][2];
    const int tid = threadIdx.x;
    const int l = tid & 63, w = tid >> 6;
    const int g = l >> 4, lm = l & 15;
    const int ow = w >> 1, nw = w & 1;
    const int o_base = ow * 64;
    const int n_base = blockIdx.x * 128 + nw * 64;

    f32x4 acc[4][4] = {};

    for (int k0 = 0; k0 < NIN; k0 += 32) {
        const int kk = k0 + g * 8;
        bf16x8 af[4], bfr[4];
        #pragma unroll
        for (int m = 0; m < 4; ++m)
            af[m] = *(const bf16x8*)&Wb[(size_t)(o_base + m * 16 + lm) * NIN + kk];
        #pragma unroll
        for (int r = 0; r < 4; ++r)
            bfr[r] = *(const bf16x8*)&Xc[(size_t)(n_base + r * 16 + lm) * NIN + kk];
        #pragma unroll
        for (int m = 0; m < 4; ++m)
            #pragma unroll
            for (int r = 0; r < 4; ++r)
                acc[m][r] = __builtin_amdgcn_mfma_f32_16x16x32_bf16(af[m], bfr[r], acc[m][r], 0, 0, 0);
    }

    // epilogue: C/D layout col(n)=lm, row(o)=g*4+reg  [verified m89/m91]
    #pragma unroll
    for (int m = 0; m < 4; ++m) {
        float s[4] = {0.f, 0.f, 0.f, 0.f}, q[4] = {0.f, 0.f, 0.f, 0.f};
        #pragma unroll
        for (int r = 0; r < 4; ++r) {
            const int n = n_base + r * 16 + lm;
            bf16x4 pk;
            #pragma unroll
            for (int j = 0; j < 4; ++j) {
                float v = acc[m][r][j];
                pk[j] = (__bf16)v;
                s[j] += v; q[j] += v * v;
            }
            *(bf16x4*)&y0[(size_t)n * NC0 + o_base + m * 16 + g * 4] = pk;
        }
        #pragma unroll
        for (int j = 0; j < 4; ++j) {
            #pragma unroll
            for (int st = 1; st < 16; st <<= 1) {
                s[j] += __shfl_xor(s[j], st);
                q[j] += __shfl_xor(q[j], st);
            }
        }
        if (lm == 0) {
            #pragma unroll
            for (int j = 0; j < 4; ++j) {
                red[0][o_base + m * 16 + g * 4 + j][nw] = s[j];
                red[1][o_base + m * 16 + g * 4 + j][nw] = q[j];
            }
        }
    }
    __syncthreads();
    if (tid < NC0) {
        atomicAdd(&sums[tid],  red[0][tid][0] + red[0][tid][1]);
        atomicAdd(&sumsq[tid], red[1][tid][0] + red[1][tid][1]);
    }
}

// ---------------------------------------------------------------------------
// Kernel 5: finalize BN stats -> scale/shift
// ---------------------------------------------------------------------------
__global__ void stats_kernel(
    const float* __restrict__ sums, const float* __restrict__ sumsq,
    const float* __restrict__ g, const float* __restrict__ be,
    float* __restrict__ scale, float* __restrict__ shift, int C)
{
    int c = blockIdx.x * blockDim.x + threadIdx.x;
    if (c < C) {
        const float invN = 1.0f / (float)NBN;
        float mean = sums[c] * invN;
        float var  = sumsq[c] * invN - mean * mean;
        float sc   = g[c] * rsqrtf(var + 1e-5f);
        scale[c] = sc;
        shift[c] = be[c] - mean * sc;
    }
}

// ---------------------------------------------------------------------------
// Kernel 6: GEMM1. B operand = relu(BN0(y0)) applied in-register on load.
// Block 512 thr (8 waves, 2o x 4n), tile 128o x 128n, K=256.
// Writes y1[o][bn] fp32 (the final output layout, pre-BN1).
// ---------------------------------------------------------------------------
__global__ __launch_bounds__(512, 4) void gemm1_mfma(
    const __bf16* __restrict__ Wb, const __bf16* __restrict__ y0,
    const float* __restrict__ scale0, const float* __restrict__ shift0,
    float* __restrict__ y1, float* __restrict__ sums, float* __restrict__ sumsq)
{
    __shared__ float red[2][NC1][4];
    const int tid = threadIdx.x;
    const int l = tid & 63, w = tid >> 6;
    const int g = l >> 4, lm = l & 15;
    const int ow = w >> 2, nw = w & 3;
    const int o_base = ow * 64;
    const int n_base = blockIdx.x * 128 + nw * 32;

    f32x4 acc[4][2] = {};

    for (int k0 = 0; k0 < NC0; k0 += 32) {
        const int kk = k0 + g * 8;
        f32x4 sc0 = *(const f32x4*)&scale0[kk];
        f32x4 sc1 = *(const f32x4*)&scale0[kk + 4];
        f32x4 sh0 = *(const f32x4*)&shift0[kk];
        f32x4 sh1 = *(const f32x4*)&shift0[kk + 4];
        bf16x8 af[4], bfr[2];
        #pragma unroll
        for (int m = 0; m < 4; ++m)
            af[m] = *(const bf16x8*)&Wb[(size_t)(o_base + m * 16 + lm) * NC0 + kk];
        #pragma unroll
        for (int r = 0; r < 2; ++r) {
            bf16x8 raw = *(const bf16x8*)&y0[(size_t)(n_base + r * 16 + lm) * NC0 + kk];
            bf16x8 bb;
            #pragma unroll
            for (int j = 0; j < 4; ++j) {
                bb[j]     = (__bf16)fmaxf((float)raw[j]     * sc0[j] + sh0[j], 0.f);
                bb[j + 4] = (__bf16)fmaxf((float)raw[j + 4] * sc1[j] + sh1[j], 0.f);
            }
            bfr[r] = bb;
        }
        #pragma unroll
        for (int m = 0; m < 4; ++m)
            #pragma unroll
            for (int r = 0; r < 2; ++r)
                acc[m][r] = __builtin_amdgcn_mfma_f32_16x16x32_bf16(af[m], bfr[r], acc[m][r], 0, 0, 0);
    }

    #pragma unroll
    for (int m = 0; m < 4; ++m) {
        float s[4] = {0.f, 0.f, 0.f, 0.f}, q[4] = {0.f, 0.f, 0.f, 0.f};
        #pragma unroll
        for (int r = 0; r < 2; ++r) {
            const int n = n_base + r * 16 + lm;
            #pragma unroll
            for (int j = 0; j < 4; ++j) {
                float v = acc[m][r][j];
                y1[(size_t)(o_base + m * 16 + g * 4 + j) * NBN + n] = v;
                s[j] += v; q[j] += v * v;
            }
        }
        #pragma unroll
        for (int j = 0; j < 4; ++j) {
            #pragma unroll
            for (int st = 1; st < 16; st <<= 1) {
                s[j] += __shfl_xor(s[j], st);
                q[j] += __shfl_xor(q[j], st);
            }
        }
        if (lm == 0) {
            #pragma unroll
            for (int j = 0; j < 4; ++j) {
                red[0][o_base + m * 16 + g * 4 + j][nw] = s[j];
                red[1][o_base + m * 16 + g * 4 + j][nw] = q[j];
            }
        }
    }
    __syncthreads();
    if (tid < NC1) {
        atomicAdd(&sums[tid],  red[0][tid][0] + red[0][tid][1] + red[0][tid][2] + red[0][tid][3]);
        atomicAdd(&sumsq[tid], red[1][tid][0] + red[1][tid][1] + red[1][tid][2] + red[1][tid][3]);
    }
}

// ---------------------------------------------------------------------------
// Kernel 7: apply BN1 + ReLU; y1 is already in out layout [b][o][n]
// ---------------------------------------------------------------------------
__global__ __launch_bounds__(256) void bnout_kernel(
    const float* __restrict__ y1, const float* __restrict__ scale1,
    const float* __restrict__ shift1, float* __restrict__ out)
{
    const size_t t = (size_t)blockIdx.x * 256 + threadIdx.x;
    const size_t e = t * 4;
    const int n = (int)(e & (NPT - 1));
    const int o = (int)((e >> 13) & (NC1 - 1));
    const int b = (int)(e >> 20);
    float4 v = *reinterpret_cast<const float4*>(&y1[(size_t)o * NBN + (size_t)b * NPT + n]);
    const float s = scale1[o], sh = shift1[o];
    float4 r;
    r.x = fmaxf(v.x * s + sh, 0.f);
    r.y = fmaxf(v.y * s + sh, 0.f);
    r.z = fmaxf(v.z * s + sh, 0.f);
    r.w = fmaxf(v.w * s + sh, 0.f);
    *reinterpret_cast<float4*>(&out[e]) = r;
}

// ---------------------------------------------------------------------------
extern "C" void kernel_launch(void* const* d_in, const int* in_sizes, int n_in,
                              void* d_out, int out_size, void* d_ws, size_t ws_size,
                              hipStream_t stream)
{
    const float* xyz1    = (const float*)d_in[0];
    const float* xyz2    = (const float*)d_in[1];
    const float* points1 = (const float*)d_in[2];
    const float* points2 = (const float*)d_in[3];
    const float* w0  = (const float*)d_in[4];
    const float* g0  = (const float*)d_in[6];
    const float* be0 = (const float*)d_in[7];
    const float* w1  = (const float*)d_in[8];
    const float* g1  = (const float*)d_in[10];
    const float* be1 = (const float*)d_in[11];

    char* ws = (char*)d_ws;
    size_t off = 0;
    int*    idx3 = (int*)(ws + off);    off += (size_t)NBN * 3 * 4;        // 768 KB
    float*  wgt3 = (float*)(ws + off);  off += (size_t)NBN * 3 * 4;        // 768 KB
    __bf16* Xc   = (__bf16*)(ws + off); off += (size_t)NBN * NIN * 2;      // 50.3 MB
    __bf16* y0   = (__bf16*)(ws + off); off += (size_t)NBN * NC0 * 2;      // 33.6 MB
    float*  y1   = (float*)(ws + off);  off += (size_t)NC1 * NBN * 4;      // 33.6 MB
    __bf16* Wb0  = (__bf16*)(ws + off); off += (size_t)NC0 * NIN * 2;      // 192 KB
    __bf16* Wb1  = (__bf16*)(ws + off); off += (size_t)NC1 * NC0 * 2;      // 64 KB
    float*  stats = (float*)(ws + off);
    float* sums0  = stats;        float* sumsq0 = stats + 256;
    float* sums1  = stats + 512;  float* sumsq1 = stats + 640;
    float* scale0 = stats + 768;  float* shift0 = stats + 1024;
    float* scale1 = stats + 1280; float* shift1 = stats + 1408;

    hipMemsetAsync(stats, 0, 768 * 4, stream);  // zero sum accumulators

    convert_w_kernel<<<dim3(NC0 * NIN / 256), 256, 0, stream>>>(w0, w1, Wb0, Wb1);
    knn_kernel      <<<dim3(NB, 64), 256, 0, stream>>>(xyz1, xyz2, idx3, wgt3);
    build_xc_kernel <<<dim3(NB, NPT / 256), 256, 0, stream>>>(points1, points2, idx3, wgt3, Xc);
    gemm0_mfma      <<<dim3(NBN / 128), 512, 0, stream>>>(Wb0, Xc, y0, sums0, sumsq0);
    stats_kernel    <<<1, 256, 0, stream>>>(sums0, sumsq0, g0, be0, scale0, shift0, NC0);
    gemm1_mfma      <<<dim3(NBN / 128), 512, 0, stream>>>(Wb1, y0, scale0, shift0, y1, sums1, sumsq1);
    stats_kernel    <<<1, 128, 0, stream>>>(sums1, sumsq1, g1, be1, scale1, shift1, NC1);
    bnout_kernel    <<<dim3(NBN * NC1 / 4 / 256), 256, 0, stream>>>(y1, scale1, shift1, (float*)d_out);
}

// Round 3
// 337.310 us; speedup vs baseline: 1.7323x; 1.3508x over previous
//
#include <hip/hip_runtime.h>

// Problem constants
#define NB   8        // batch
#define NPT  8192     // N query points
#define NS   2048     // S source points
#define ND1  128      // points1 channels
#define ND2  256      // points2 channels
#define NIN  384      // concat channels
#define NC0  256      // MLP[0]
#define NC1  128      // MLP[1]
#define NBN  (NB*NPT) // 65536 total columns

typedef __bf16 bf16x8 __attribute__((ext_vector_type(8)));
typedef __bf16 bf16x4 __attribute__((ext_vector_type(4)));
typedef float  f32x4  __attribute__((ext_vector_type(4)));

// ---------------------------------------------------------------------------
// Kernel 1: 3-NN + inverse-distance weights.
// grid (NB, 128): 64 queries/block, 256 thr = 4 threads/query, each scanning
// S/4=512 candidates. pts[s]=(x,y,z,|p|^2) -> 1 broadcast ds_read_b128/cand.
// Branchless top-3 (3 cmp + 5 cndmask + min/med network). Key drops the
// per-query |p1|^2 (monotonic); re-added before weights.
// ---------------------------------------------------------------------------
__global__ __launch_bounds__(256) void knn_kernel(
    const float* __restrict__ xyz1, const float* __restrict__ xyz2,
    int* __restrict__ idx3, float* __restrict__ wgt3)
{
    __shared__ float4 pts[NS];      // 32 KB
    __shared__ float md[64][4][3];
    __shared__ int   mi[64][4][3];

    const int b  = blockIdx.x;
    const int qt = blockIdx.y;
    const float* x2 = xyz2 + (size_t)b * 3 * NS;
    for (int s = threadIdx.x; s < NS; s += 256) {
        float x = x2[s], y = x2[NS + s], z = x2[2 * NS + s];
        pts[s] = make_float4(x, y, z, x * x + y * y + z * z);
    }
    __syncthreads();

    const int q    = threadIdx.x & 63;
    const int part = threadIdx.x >> 6;      // 0..3
    const int n    = qt * 64 + q;
    const float* x1 = xyz1 + (size_t)b * 3 * NPT;
    const float px = x1[n], py = x1[NPT + n], pz = x1[2 * NPT + n];

    float d0 = 3e38f, d1 = 3e38f, d2 = 3e38f;
    int   i0 = 0, i1 = 0, i2 = 0;
    const int sbeg = part * (NS / 4);
    #pragma unroll 2
    for (int s = sbeg; s < sbeg + NS / 4; ++s) {
        float4 p = pts[s];
        float t = px * p.x;
        t = fmaf(py, p.y, t);
        t = fmaf(pz, p.z, t);
        float d = fmaf(-2.f, t, p.w);       // key = |p2|^2 - 2 p1.p2
        bool c0 = d < d0, c1 = d < d1, c2 = d < d2;
        i2 = c1 ? i1 : (c2 ? s : i2);
        i1 = c0 ? i0 : (c1 ? s : i1);
        i0 = c0 ? s  : i0;
        d2 = fminf(fmaxf(d, d1), d2);       // med3(d1,d2,d)
        d1 = fminf(fmaxf(d, d0), d1);       // med3(d0,d1,d)
        d0 = fminf(d, d0);
    }
    md[q][part][0] = d0; md[q][part][1] = d1; md[q][part][2] = d2;
    mi[q][part][0] = i0; mi[q][part][1] = i1; mi[q][part][2] = i2;
    __syncthreads();

    if (threadIdx.x < 64) {
        // 4-way merge of sorted triples; ascending-list scan with strict <
        // keeps lowest-s on ties (chunks are s-ordered) = top_k tie-break.
        int hp[4] = {0, 0, 0, 0};
        float rd[3]; int ri[3];
        #pragma unroll
        for (int k = 0; k < 3; ++k) {
            float best = 3.0e38f; int bl = 0;
            #pragma unroll
            for (int l = 0; l < 4; ++l) {
                float dv = md[q][l][hp[l]];
                if (dv < best) { best = dv; bl = l; }
            }
            rd[k] = best; ri[k] = mi[q][bl][hp[bl]]; hp[bl]++;
        }
        const float p1sq = px * px + py * py + pz * pz;
        float r0 = 1.0f / (rd[0] + p1sq + 1e-8f);
        float r1 = 1.0f / (rd[1] + p1sq + 1e-8f);
        float r2 = 1.0f / (rd[2] + p1sq + 1e-8f);
        float inv = 1.0f / (r0 + r1 + r2);
        size_t base = ((size_t)b * NPT + n) * 3;
        idx3[base] = ri[0]; idx3[base + 1] = ri[1]; idx3[base + 2] = ri[2];
        wgt3[base] = r0 * inv; wgt3[base + 1] = r1 * inv; wgt3[base + 2] = r2 * inv;
    }
}

// ---------------------------------------------------------------------------
// Kernel 2: transpose points2 [b][d][s] fp32 -> p2t [b][s][d] bf16 so the
// interp gather streams contiguous rows. 64x64 LDS tile, padded stride.
// grid (NB, 128): y&31 = s-tile, y>>5 = d-tile.
// ---------------------------------------------------------------------------
__global__ __launch_bounds__(256) void transpose_p2_kernel(
    const float* __restrict__ p2, __bf16* __restrict__ p2t)
{
    __shared__ float tile[64][65];
    const int b  = blockIdx.x;
    const int ts = (blockIdx.y & 31) * 64;
    const int td = (blockIdx.y >> 5) * 64;
    const int sl = threadIdx.x & 63, dl = threadIdx.x >> 6;
    #pragma unroll
    for (int i = 0; i < 16; ++i)
        tile[dl + 4 * i][sl] = p2[((size_t)b * ND2 + td + dl + 4 * i) * NS + ts + sl];
    __syncthreads();
    const int dl2 = threadIdx.x & 63, sl2 = threadIdx.x >> 6;
    #pragma unroll
    for (int i = 0; i < 16; ++i)
        p2t[((size_t)b * NS + ts + sl2 + 4 * i) * ND2 + td + dl2] =
            (__bf16)tile[dl2][sl2 + 4 * i];
}

// ---------------------------------------------------------------------------
// Kernel 3: build Xc[n][c] bf16 = concat(points1, interp(p2t)).
// p1: coalesced column reads. p2t: 3 contiguous bf16 rows per thread,
// 16B chunks (L1-friendly), weighted-sum in fp32.
// ---------------------------------------------------------------------------
__global__ __launch_bounds__(256) void build_xc_kernel(
    const float* __restrict__ points1, const __bf16* __restrict__ p2t,
    const int* __restrict__ idx3, const float* __restrict__ wgt3,
    __bf16* __restrict__ Xc)
{
    const int b = blockIdx.x;
    const int n = blockIdx.y * 256 + threadIdx.x;
    const size_t base3 = ((size_t)b * NPT + n) * 3;
    const int i0 = idx3[base3], i1 = idx3[base3 + 1], i2 = idx3[base3 + 2];
    const float w0 = wgt3[base3], w1 = wgt3[base3 + 1], w2 = wgt3[base3 + 2];

    __bf16* dst = Xc + ((size_t)b * NPT + n) * NIN;
    const float* p1 = points1 + (size_t)b * ND1 * NPT + n;
    #pragma unroll 2
    for (int c0 = 0; c0 < ND1; c0 += 8) {
        bf16x8 v;
        #pragma unroll
        for (int j = 0; j < 8; ++j) v[j] = (__bf16)p1[(size_t)(c0 + j) * NPT];
        *(bf16x8*)(dst + c0) = v;
    }
    const __bf16* r0 = p2t + ((size_t)b * NS + i0) * ND2;
    const __bf16* r1 = p2t + ((size_t)b * NS + i1) * ND2;
    const __bf16* r2 = p2t + ((size_t)b * NS + i2) * ND2;
    #pragma unroll 2
    for (int d0 = 0; d0 < ND2; d0 += 8) {
        bf16x8 a = *(const bf16x8*)(r0 + d0);
        bf16x8 c = *(const bf16x8*)(r1 + d0);
        bf16x8 e = *(const bf16x8*)(r2 + d0);
        bf16x8 v;
        #pragma unroll
        for (int j = 0; j < 8; ++j)
            v[j] = (__bf16)(w0 * (float)a[j] + w1 * (float)c[j] + w2 * (float)e[j]);
        *(bf16x8*)(dst + ND1 + d0) = v;
    }
}

// ---------------------------------------------------------------------------
// Kernel 4: convert weights to bf16 [o][k]
// ---------------------------------------------------------------------------
__global__ __launch_bounds__(256) void convert_w_kernel(
    const float* __restrict__ w0, const float* __restrict__ w1,
    __bf16* __restrict__ Wb0, __bf16* __restrict__ Wb1)
{
    const int t = blockIdx.x * 256 + threadIdx.x;
    if (t < NC0 * NIN) Wb0[t] = (__bf16)w0[t];
    if (t < NC1 * NC0) Wb1[t] = (__bf16)w1[t];
}

// ---------------------------------------------------------------------------
// Kernel 5: GEMM0 via 16x16x32 bf16 MFMA, LDS-free. 8 waves (4o x 2n),
// tile 256o x 128n, K=384. Writes y0[n][o] bf16. Bias skipped (BN cancels).
// ---------------------------------------------------------------------------
__global__ __launch_bounds__(512, 4) void gemm0_mfma(
    const __bf16* __restrict__ Wb, const __bf16* __restrict__ Xc,
    __bf16* __restrict__ y0, float* __restrict__ sums, float* __restrict__ sumsq)
{
    __shared__ float red[2][NC0][2];
    const int tid = threadIdx.x;
    const int l = tid & 63, w = tid >> 6;
    const int g = l >> 4, lm = l & 15;
    const int ow = w >> 1, nw = w & 1;
    const int o_base = ow * 64;
    const int n_base = blockIdx.x * 128 + nw * 64;

    f32x4 acc[4][4] = {};

    for (int k0 = 0; k0 < NIN; k0 += 32) {
        const int kk = k0 + g * 8;
        bf16x8 af[4], bfr[4];
        #pragma unroll
        for (int m = 0; m < 4; ++m)
            af[m] = *(const bf16x8*)&Wb[(size_t)(o_base + m * 16 + lm) * NIN + kk];
        #pragma unroll
        for (int r = 0; r < 4; ++r)
            bfr[r] = *(const bf16x8*)&Xc[(size_t)(n_base + r * 16 + lm) * NIN + kk];
        #pragma unroll
        for (int m = 0; m < 4; ++m)
            #pragma unroll
            for (int r = 0; r < 4; ++r)
                acc[m][r] = __builtin_amdgcn_mfma_f32_16x16x32_bf16(af[m], bfr[r], acc[m][r], 0, 0, 0);
    }

    #pragma unroll
    for (int m = 0; m < 4; ++m) {
        float s[4] = {0.f, 0.f, 0.f, 0.f}, q[4] = {0.f, 0.f, 0.f, 0.f};
        #pragma unroll
        for (int r = 0; r < 4; ++r) {
            const int n = n_base + r * 16 + lm;
            bf16x4 pk;
            #pragma unroll
            for (int j = 0; j < 4; ++j) {
                float v = acc[m][r][j];
                pk[j] = (__bf16)v;
                s[j] += v; q[j] += v * v;
            }
            *(bf16x4*)&y0[(size_t)n * NC0 + o_base + m * 16 + g * 4] = pk;
        }
        #pragma unroll
        for (int j = 0; j < 4; ++j) {
            #pragma unroll
            for (int st = 1; st < 16; st <<= 1) {
                s[j] += __shfl_xor(s[j], st);
                q[j] += __shfl_xor(q[j], st);
            }
        }
        if (lm == 0) {
            #pragma unroll
            for (int j = 0; j < 4; ++j) {
                red[0][o_base + m * 16 + g * 4 + j][nw] = s[j];
                red[1][o_base + m * 16 + g * 4 + j][nw] = q[j];
            }
        }
    }
    __syncthreads();
    if (tid < NC0) {
        atomicAdd(&sums[tid],  red[0][tid][0] + red[0][tid][1]);
        atomicAdd(&sumsq[tid], red[1][tid][0] + red[1][tid][1]);
    }
}

// ---------------------------------------------------------------------------
// Kernel 6: finalize BN stats -> scale/shift
// ---------------------------------------------------------------------------
__global__ void stats_kernel(
    const float* __restrict__ sums, const float* __restrict__ sumsq,
    const float* __restrict__ g, const float* __restrict__ be,
    float* __restrict__ scale, float* __restrict__ shift, int C)
{
    int c = blockIdx.x * blockDim.x + threadIdx.x;
    if (c < C) {
        const float invN = 1.0f / (float)NBN;
        float mean = sums[c] * invN;
        float var  = sumsq[c] * invN - mean * mean;
        float sc   = g[c] * rsqrtf(var + 1e-5f);
        scale[c] = sc;
        shift[c] = be[c] - mean * sc;
    }
}

// ---------------------------------------------------------------------------
// Kernel 7: GEMM1. B = relu(BN0(y0)) in-register. Writes y1[o][bn] bf16.
// ---------------------------------------------------------------------------
__global__ __launch_bounds__(512, 4) void gemm1_mfma(
    const __bf16* __restrict__ Wb, const __bf16* __restrict__ y0,
    const float* __restrict__ scale0, const float* __restrict__ shift0,
    __bf16* __restrict__ y1, float* __restrict__ sums, float* __restrict__ sumsq)
{
    __shared__ float red[2][NC1][4];
    const int tid = threadIdx.x;
    const int l = tid & 63, w = tid >> 6;
    const int g = l >> 4, lm = l & 15;
    const int ow = w >> 2, nw = w & 3;
    const int o_base = ow * 64;
    const int n_base = blockIdx.x * 128 + nw * 32;

    f32x4 acc[4][2] = {};

    for (int k0 = 0; k0 < NC0; k0 += 32) {
        const int kk = k0 + g * 8;
        f32x4 sc0 = *(const f32x4*)&scale0[kk];
        f32x4 sc1 = *(const f32x4*)&scale0[kk + 4];
        f32x4 sh0 = *(const f32x4*)&shift0[kk];
        f32x4 sh1 = *(const f32x4*)&shift0[kk + 4];
        bf16x8 af[4], bfr[2];
        #pragma unroll
        for (int m = 0; m < 4; ++m)
            af[m] = *(const bf16x8*)&Wb[(size_t)(o_base + m * 16 + lm) * NC0 + kk];
        #pragma unroll
        for (int r = 0; r < 2; ++r) {
            bf16x8 raw = *(const bf16x8*)&y0[(size_t)(n_base + r * 16 + lm) * NC0 + kk];
            bf16x8 bb;
            #pragma unroll
            for (int j = 0; j < 4; ++j) {
                bb[j]     = (__bf16)fmaxf((float)raw[j]     * sc0[j] + sh0[j], 0.f);
                bb[j + 4] = (__bf16)fmaxf((float)raw[j + 4] * sc1[j] + sh1[j], 0.f);
            }
            bfr[r] = bb;
        }
        #pragma unroll
        for (int m = 0; m < 4; ++m)
            #pragma unroll
            for (int r = 0; r < 2; ++r)
                acc[m][r] = __builtin_amdgcn_mfma_f32_16x16x32_bf16(af[m], bfr[r], acc[m][r], 0, 0, 0);
    }

    #pragma unroll
    for (int m = 0; m < 4; ++m) {
        float s[4] = {0.f, 0.f, 0.f, 0.f}, q[4] = {0.f, 0.f, 0.f, 0.f};
        #pragma unroll
        for (int r = 0; r < 2; ++r) {
            const int n = n_base + r * 16 + lm;
            #pragma unroll
            for (int j = 0; j < 4; ++j) {
                float v = acc[m][r][j];
                y1[(size_t)(o_base + m * 16 + g * 4 + j) * NBN + n] = (__bf16)v;
                s[j] += v; q[j] += v * v;
            }
        }
        #pragma unroll
        for (int j = 0; j < 4; ++j) {
            #pragma unroll
            for (int st = 1; st < 16; st <<= 1) {
                s[j] += __shfl_xor(s[j], st);
                q[j] += __shfl_xor(q[j], st);
            }
        }
        if (lm == 0) {
            #pragma unroll
            for (int j = 0; j < 4; ++j) {
                red[0][o_base + m * 16 + g * 4 + j][nw] = s[j];
                red[1][o_base + m * 16 + g * 4 + j][nw] = q[j];
            }
        }
    }
    __syncthreads();
    if (tid < NC1) {
        atomicAdd(&sums[tid],  red[0][tid][0] + red[0][tid][1] + red[0][tid][2] + red[0][tid][3]);
        atomicAdd(&sumsq[tid], red[1][tid][0] + red[1][tid][1] + red[1][tid][2] + red[1][tid][3]);
    }
}

// ---------------------------------------------------------------------------
// Kernel 8: apply BN1 + ReLU; y1 bf16 [o][b*N+n] -> out fp32 [b][o][n]
// ---------------------------------------------------------------------------
__global__ __launch_bounds__(256) void bnout_kernel(
    const __bf16* __restrict__ y1, const float* __restrict__ scale1,
    const float* __restrict__ shift1, float* __restrict__ out)
{
    const size_t t = (size_t)blockIdx.x * 256 + threadIdx.x;
    const size_t e = t * 8;
    const int n = (int)(e & (NPT - 1));
    const int o = (int)((e >> 13) & (NC1 - 1));
    const int b = (int)(e >> 20);
    bf16x8 v = *(const bf16x8*)&y1[(size_t)o * NBN + (size_t)b * NPT + n];
    const float s = scale1[o], sh = shift1[o];
    f32x4 r0, r1;
    #pragma unroll
    for (int j = 0; j < 4; ++j) {
        r0[j] = fmaxf((float)v[j]     * s + sh, 0.f);
        r1[j] = fmaxf((float)v[j + 4] * s + sh, 0.f);
    }
    *(f32x4*)&out[e]     = r0;
    *(f32x4*)&out[e + 4] = r1;
}

// ---------------------------------------------------------------------------
extern "C" void kernel_launch(void* const* d_in, const int* in_sizes, int n_in,
                              void* d_out, int out_size, void* d_ws, size_t ws_size,
                              hipStream_t stream)
{
    const float* xyz1    = (const float*)d_in[0];
    const float* xyz2    = (const float*)d_in[1];
    const float* points1 = (const float*)d_in[2];
    const float* points2 = (const float*)d_in[3];
    const float* w0  = (const float*)d_in[4];
    const float* g0  = (const float*)d_in[6];
    const float* be0 = (const float*)d_in[7];
    const float* w1  = (const float*)d_in[8];
    const float* g1  = (const float*)d_in[10];
    const float* be1 = (const float*)d_in[11];

    char* ws = (char*)d_ws;
    size_t off = 0;
    int*    idx3 = (int*)(ws + off);    off += (size_t)NBN * 3 * 4;        // 768 KB
    float*  wgt3 = (float*)(ws + off);  off += (size_t)NBN * 3 * 4;        // 768 KB
    __bf16* Xc   = (__bf16*)(ws + off); off += (size_t)NBN * NIN * 2;      // 50.3 MB
    __bf16* y0   = (__bf16*)(ws + off); off += (size_t)NBN * NC0 * 2;      // 33.6 MB
    __bf16* y1   = (__bf16*)(ws + off); off += (size_t)NC1 * NBN * 2;      // 16.8 MB
    __bf16* p2t  = (__bf16*)(ws + off); off += (size_t)NB * NS * ND2 * 2;  // 8.4 MB
    __bf16* Wb0  = (__bf16*)(ws + off); off += (size_t)NC0 * NIN * 2;      // 192 KB
    __bf16* Wb1  = (__bf16*)(ws + off); off += (size_t)NC1 * NC0 * 2;      // 64 KB
    float*  stats = (float*)(ws + off);
    float* sums0  = stats;        float* sumsq0 = stats + 256;
    float* sums1  = stats + 512;  float* sumsq1 = stats + 640;
    float* scale0 = stats + 768;  float* shift0 = stats + 1024;
    float* scale1 = stats + 1280; float* shift1 = stats + 1408;

    hipMemsetAsync(stats, 0, 768 * 4, stream);  // zero sum accumulators

    convert_w_kernel   <<<dim3(NC0 * NIN / 256), 256, 0, stream>>>(w0, w1, Wb0, Wb1);
    transpose_p2_kernel<<<dim3(NB, 128), 256, 0, stream>>>(points2, p2t);
    knn_kernel         <<<dim3(NB, 128), 256, 0, stream>>>(xyz1, xyz2, idx3, wgt3);
    build_xc_kernel    <<<dim3(NB, NPT / 256), 256, 0, stream>>>(points1, p2t, idx3, wgt3, Xc);
    gemm0_mfma         <<<dim3(NBN / 128), 512, 0, stream>>>(Wb0, Xc, y0, sums0, sumsq0);
    stats_kernel       <<<1, 256, 0, stream>>>(sums0, sumsq0, g0, be0, scale0, shift0, NC0);
    gemm1_mfma         <<<dim3(NBN / 128), 512, 0, stream>>>(Wb1, y0, scale0, shift0, y1, sums1, sumsq1);
    stats_kernel       <<<1, 128, 0, stream>>>(sums1, sumsq1, g1, be1, scale1, shift1, NC1);
    bnout_kernel       <<<dim3(NBN * NC1 / 8 / 256), 256, 0, stream>>>(y1, scale1, shift1, (float*)d_out);
}